// Round 12
// baseline (625.106 us; speedup 1.0000x reference)
//
#include <hip/hip_runtime.h>
#include <hip/hip_bf16.h>

// Round 12: revert to R10 structure (602 us) + exp2 softmax.
//  - q pre-scaled by SCALE*log2(e); attention uses exp2f (v_exp_f32 native,
//    no per-element mul). Pool path same treatment (log2-domain max/merge).
//  - gemm64 everywhere (R11's 128-tile was neutral->reverted).

#define NLAYER 6
#define DMODEL 256
#define NHEAD  8
#define DHEAD  32
#define DFF    1024
#define NCTX   64
#define NBATCH 2
#define SEQ    2048
#define NROWS  (NBATCH*SEQ)          // 4096
#define SCALE  0.17677669529663687f  // 1/sqrt(32)
#define LOG2E  1.4426950408889634f
#define NCHUNK 16

typedef short s16x8 __attribute__((ext_vector_type(8)));
typedef short s16x4 __attribute__((ext_vector_type(4)));
typedef float f32x4 __attribute__((ext_vector_type(4)));
using bf16 = __hip_bfloat16;

__device__ __forceinline__ float gelu_exact(float x) {
    return 0.5f * x * (1.0f + erff(x * 0.7071067811865475f));
}
__device__ __forceinline__ short bf16_bits(float x) {
    bf16 h = __float2bfloat16(x);
    return *(short*)&h;
}
__device__ __forceinline__ float bfb2f(short s) {
    return __uint_as_float(((unsigned)(unsigned short)s) << 16);
}
__device__ __forceinline__ void load16_lds(const void* g, void* l) {
    __builtin_amdgcn_global_load_lds(
        (const __attribute__((address_space(1))) void*)g,
        (__attribute__((address_space(3))) void*)l, 16, 0, 0);
}

__device__ __forceinline__ void breduce_sum2(float v1, float v2, float* r1, float* r2,
                                             float& o1, float& o2) {
    const int t = threadIdx.x;
    r1[t] = v1; r2[t] = v2;
    __syncthreads();
    for (int s = 128; s > 0; s >>= 1) {
        if (t < s) { r1[t] += r1[t + s]; r2[t] += r2[t + s]; }
        __syncthreads();
    }
    o1 = r1[0]; o2 = r2[0];
    __syncthreads();
}
__device__ __forceinline__ float breduce_max(float v, float* r1) {
    const int t = threadIdx.x;
    r1[t] = v; __syncthreads();
    for (int s = 128; s > 0; s >>= 1) {
        if (t < s) r1[t] = fmaxf(r1[t], r1[t + s]);
        __syncthreads();
    }
    float res = r1[0]; __syncthreads();
    return res;
}
__device__ __forceinline__ float breduce_sum(float v, float* r1) {
    const int t = threadIdx.x;
    r1[t] = v; __syncthreads();
    for (int s = 128; s > 0; s >>= 1) {
        if (t < s) r1[t] += r1[t + s];
        __syncthreads();
    }
    float res = r1[0]; __syncthreads();
    return res;
}

// ---------------------------------------------------------------------------
// All weight transposes in one launch. W (K x N fp32) -> WT (N x K bf16).
__global__ __launch_bounds__(256) void wt_all_kernel(
        const float* __restrict__ Wqkv, const float* __restrict__ Wout,
        const float* __restrict__ fW1, const float* __restrict__ fW2,
        const float* __restrict__ pWk, const float* __restrict__ pWv,
        const float* __restrict__ tokW2,
        bf16* __restrict__ WTq, bf16* __restrict__ WTo, bf16* __restrict__ WT1,
        bf16* __restrict__ WT2, bf16* __restrict__ WTpk, bf16* __restrict__ WTpv,
        bf16* __restrict__ WTt2) {
    int bid = blockIdx.x;
    const float* W; bf16* WT; int K, N, kt;
    if (bid < 1152)      { W = Wqkv;  WT = WTq;  K = 256;  N = 768;  kt = 8;  }
    else if (bid < 1536) { W = Wout;  WT = WTo;  K = 256;  N = 256;  kt = 8;  bid -= 1152; }
    else if (bid < 3072) { W = fW1;   WT = WT1;  K = 256;  N = 1024; kt = 8;  bid -= 1536; }
    else if (bid < 4608) { W = fW2;   WT = WT2;  K = 1024; N = 256;  kt = 32; bid -= 3072; }
    else if (bid < 4672) { W = pWk;   WT = WTpk; K = 256;  N = 256;  kt = 8;  bid -= 4608; }
    else if (bid < 4736) { W = pWv;   WT = WTpv; K = 256;  N = 256;  kt = 8;  bid -= 4672; }
    else                 { W = tokW2; WT = WTt2; K = 256;  N = 256;  kt = 8;  bid -= 4736; }
    const int per = kt * (N >> 5);
    const int zz = bid / per;
    const int rel = bid % per;
    const int k0 = (rel % kt) * 32, n0 = (rel / kt) * 32;
    W  += (size_t)zz * K * N;
    WT += (size_t)zz * K * N;
    __shared__ float tile[32][33];
    const int tx = threadIdx.x & 31, ty = threadIdx.x >> 5;
    #pragma unroll
    for (int i = 0; i < 32; i += 8)
        tile[ty + i][tx] = W[(size_t)(k0 + ty + i) * N + n0 + tx];
    __syncthreads();
    #pragma unroll
    for (int i = 0; i < 32; i += 8)
        WT[(size_t)(n0 + ty + i) * K + k0 + tx] = __float2bfloat16(tile[tx][ty + i]);
}

// ---------------------------------------------------------------------------
__global__ __launch_bounds__(256) void tok_hid_kernel(
        const float* __restrict__ feat, const int* __restrict__ bid,
        const float* __restrict__ emb, const float* __restrict__ W1,
        const float* __restrict__ b1, bf16* __restrict__ h8,
        float* __restrict__ cosb, float* __restrict__ sinb) {
    const int row0 = blockIdx.x * 4;
    const int t = threadIdx.x;
    __shared__ float tok[4][14];
    if (t < 56) {
        const int r = t / 14, i = t % 14;
        const int row = row0 + r;
        tok[r][i] = (i < 6) ? feat[row * 6 + i] : emb[bid[row] * 8 + (i - 6)];
    }
    if (t < 64) {
        const int r = t >> 4, i = t & 15;
        const int row = row0 + r;
        const float pos = feat[row * 6] * 512.0f;
        const float invf = expf(-9.210340371976184f * (float)i * (1.0f / 16.0f));
        const float fr = pos * invf;
        cosb[row * 16 + i] = cosf(fr);
        sinb[row * 16 + i] = sinf(fr);
    }
    __syncthreads();
    float w[14];
    #pragma unroll
    for (int k2 = 0; k2 < 14; k2++) w[k2] = W1[k2 * DMODEL + t];
    const float bb = b1[t];
    #pragma unroll
    for (int r = 0; r < 4; r++) {
        float acc = bb;
        #pragma unroll
        for (int k2 = 0; k2 < 14; k2++) acc += tok[r][k2] * w[k2];
        h8[(size_t)(row0 + r) * DMODEL + t] = __float2bfloat16(gelu_exact(acc));
    }
}

// ---------------------------------------------------------------------------
__global__ __launch_bounds__(256) void ln_bf16_kernel(
        const float* __restrict__ x, const float* __restrict__ g,
        const float* __restrict__ b, bf16* __restrict__ y) {
    const int wave = threadIdx.x >> 6, lane = threadIdx.x & 63;
    const int row = blockIdx.x * 4 + wave;
    const float4 xv = *(const float4*)(x + (size_t)row * DMODEL + lane * 4);
    float s1 = xv.x + xv.y + xv.z + xv.w;
    float s2 = xv.x * xv.x + xv.y * xv.y + xv.z * xv.z + xv.w * xv.w;
    #pragma unroll
    for (int off = 32; off >= 1; off >>= 1) {
        s1 += __shfl_xor(s1, off);
        s2 += __shfl_xor(s2, off);
    }
    const float mu = s1 * (1.0f / DMODEL);
    const float var = s2 * (1.0f / DMODEL) - mu * mu;
    const float rstd = rsqrtf(var + 1e-5f);
    const float4 gv = *(const float4*)(g + lane * 4);
    const float4 bv = *(const float4*)(b + lane * 4);
    s16x4 o;
    o.x = bf16_bits((xv.x - mu) * rstd * gv.x + bv.x);
    o.y = bf16_bits((xv.y - mu) * rstd * gv.y + bv.y);
    o.z = bf16_bits((xv.z - mu) * rstd * gv.z + bv.z);
    o.w = bf16_bits((xv.w - mu) * rstd * gv.w + bv.w);
    *(s16x4*)(y + (size_t)row * DMODEL + lane * 4) = o;
}

// ---------------------------------------------------------------------------
// Generic MFMA GEMM. MODE 0: bf16; 1: += fp32; 2: gelu->bf16; 3: fp32.
template<int MODE>
__global__ __launch_bounds__(256) void gemm64_kernel(
        const bf16* __restrict__ A, const bf16* __restrict__ WT,
        const float* __restrict__ bias, void* __restrict__ out,
        int K, int ldc) {
    __shared__ __align__(16) bf16 As[64 * 64];
    __shared__ __align__(16) bf16 Ws[64 * 64];
    const int tid = threadIdx.x;
    const int lane = tid & 63, wave = tid >> 6;
    const int quad = lane >> 4, l16 = lane & 15;
    const int wr = wave >> 1, wc = wave & 1;
    const int m0 = blockIdx.x * 64, n0 = blockIdx.y * 64;
    const int cg = lane & 7;
    const int r0s = wave * 16 + (lane >> 3);
    f32x4 c00 = {0.f,0.f,0.f,0.f}, c01 = {0.f,0.f,0.f,0.f};
    f32x4 c10 = {0.f,0.f,0.f,0.f}, c11 = {0.f,0.f,0.f,0.f};

    for (int k0 = 0; k0 < K; k0 += 64) {
        __syncthreads();
        #pragma unroll
        for (int j = 0; j < 2; j++) {
            const int r = r0s + j * 8;
            const int kg = cg ^ (r & 7);
            load16_lds(A  + (size_t)(m0 + r) * K + k0 + kg * 8,
                       As + wave * 1024 + j * 512);
            load16_lds(WT + (size_t)(n0 + r) * K + k0 + kg * 8,
                       Ws + wave * 1024 + j * 512);
        }
        __syncthreads();
        #pragma unroll
        for (int kk = 0; kk < 64; kk += 32) {
            const int kg = (kk >> 3) + quad;
            const int ra0 = wr * 32 + l16, ra1 = ra0 + 16;
            const int rb0 = wc * 32 + l16, rb1 = rb0 + 16;
            const s16x8 a0 = *(const s16x8*)(As + ra0 * 64 + ((kg ^ (ra0 & 7)) << 3));
            const s16x8 a1 = *(const s16x8*)(As + ra1 * 64 + ((kg ^ (ra1 & 7)) << 3));
            const s16x8 b0 = *(const s16x8*)(Ws + rb0 * 64 + ((kg ^ (rb0 & 7)) << 3));
            const s16x8 b1 = *(const s16x8*)(Ws + rb1 * 64 + ((kg ^ (rb1 & 7)) << 3));
            c00 = __builtin_amdgcn_mfma_f32_16x16x32_bf16(a0, b0, c00, 0, 0, 0);
            c01 = __builtin_amdgcn_mfma_f32_16x16x32_bf16(a0, b1, c01, 0, 0, 0);
            c10 = __builtin_amdgcn_mfma_f32_16x16x32_bf16(a1, b0, c10, 0, 0, 0);
            c11 = __builtin_amdgcn_mfma_f32_16x16x32_bf16(a1, b1, c11, 0, 0, 0);
        }
    }
    const int nb = n0 + wc * 32;
    const float bias0 = bias[nb + l16], bias1 = bias[nb + 16 + l16];
    #pragma unroll
    for (int i = 0; i < 4; i++) {
        const int mlo = m0 + wr * 32 + quad * 4 + i;
        const int mhi = mlo + 16;
        const float v00 = c00[i] + bias0, v01 = c01[i] + bias1;
        const float v10 = c10[i] + bias0, v11 = c11[i] + bias1;
        if (MODE == 1) {
            float* C = (float*)out;
            C[(size_t)mlo * ldc + nb + l16]      += v00;
            C[(size_t)mlo * ldc + nb + 16 + l16] += v01;
            C[(size_t)mhi * ldc + nb + l16]      += v10;
            C[(size_t)mhi * ldc + nb + 16 + l16] += v11;
        } else if (MODE == 3) {
            float* C = (float*)out;
            C[(size_t)mlo * ldc + nb + l16]      = v00;
            C[(size_t)mlo * ldc + nb + 16 + l16] = v01;
            C[(size_t)mhi * ldc + nb + l16]      = v10;
            C[(size_t)mhi * ldc + nb + 16 + l16] = v11;
        } else if (MODE == 0) {
            bf16* C = (bf16*)out;
            C[(size_t)mlo * ldc + nb + l16]      = __float2bfloat16(v00);
            C[(size_t)mlo * ldc + nb + 16 + l16] = __float2bfloat16(v01);
            C[(size_t)mhi * ldc + nb + l16]      = __float2bfloat16(v10);
            C[(size_t)mhi * ldc + nb + 16 + l16] = __float2bfloat16(v11);
        } else {
            bf16* C = (bf16*)out;
            C[(size_t)mlo * ldc + nb + l16]      = __float2bfloat16(gelu_exact(v00));
            C[(size_t)mlo * ldc + nb + 16 + l16] = __float2bfloat16(gelu_exact(v01));
            C[(size_t)mhi * ldc + nb + l16]      = __float2bfloat16(gelu_exact(v10));
            C[(size_t)mhi * ldc + nb + 16 + l16] = __float2bfloat16(gelu_exact(v11));
        }
    }
}

// ---------------------------------------------------------------------------
// QKV GEMM with fused RoPE epilogue + direct v^T store. Grid (64, 12).
// q is pre-scaled by SCALE*LOG2E (exp2-domain softmax downstream).
__global__ __launch_bounds__(256) void gemm_qkv_kernel(
        const bf16* __restrict__ A, const bf16* __restrict__ WT,
        const float* __restrict__ bias, const float* __restrict__ cosb,
        const float* __restrict__ sinb, bf16* __restrict__ qo,
        bf16* __restrict__ ko, bf16* __restrict__ vo) {
    __shared__ __align__(16) bf16 As[64 * 64];
    __shared__ __align__(16) bf16 Ws[64 * 64];
    const int tid = threadIdx.x;
    const int lane = tid & 63, wave = tid >> 6;
    const int quad = lane >> 4, l16 = lane & 15;
    const int wr = wave >> 1, wc = wave & 1;
    const int m0 = blockIdx.x * 64, n0 = blockIdx.y * 64;
    const int cg = lane & 7;
    const int r0s = wave * 16 + (lane >> 3);
    f32x4 c00 = {0.f,0.f,0.f,0.f}, c01 = {0.f,0.f,0.f,0.f};
    f32x4 c10 = {0.f,0.f,0.f,0.f}, c11 = {0.f,0.f,0.f,0.f};
    const int K = DMODEL;

    for (int k0 = 0; k0 < K; k0 += 64) {
        __syncthreads();
        #pragma unroll
        for (int j = 0; j < 2; j++) {
            const int r = r0s + j * 8;
            const int kg = cg ^ (r & 7);
            load16_lds(A  + (size_t)(m0 + r) * K + k0 + kg * 8,
                       As + wave * 1024 + j * 512);
            load16_lds(WT + (size_t)(n0 + r) * K + k0 + kg * 8,
                       Ws + wave * 1024 + j * 512);
        }
        __syncthreads();
        #pragma unroll
        for (int kk = 0; kk < 64; kk += 32) {
            const int kg = (kk >> 3) + quad;
            const int ra0 = wr * 32 + l16, ra1 = ra0 + 16;
            const int rb0 = wc * 32 + l16, rb1 = rb0 + 16;
            const s16x8 a0 = *(const s16x8*)(As + ra0 * 64 + ((kg ^ (ra0 & 7)) << 3));
            const s16x8 a1 = *(const s16x8*)(As + ra1 * 64 + ((kg ^ (ra1 & 7)) << 3));
            const s16x8 b0 = *(const s16x8*)(Ws + rb0 * 64 + ((kg ^ (rb0 & 7)) << 3));
            const s16x8 b1 = *(const s16x8*)(Ws + rb1 * 64 + ((kg ^ (rb1 & 7)) << 3));
            c00 = __builtin_amdgcn_mfma_f32_16x16x32_bf16(a0, b0, c00, 0, 0, 0);
            c01 = __builtin_amdgcn_mfma_f32_16x16x32_bf16(a0, b1, c01, 0, 0, 0);
            c10 = __builtin_amdgcn_mfma_f32_16x16x32_bf16(a1, b0, c10, 0, 0, 0);
            c11 = __builtin_amdgcn_mfma_f32_16x16x32_bf16(a1, b1, c11, 0, 0, 0);
        }
    }
    const int nb = n0 + wc * 32;
    const float bias0 = bias[nb + l16], bias1 = bias[nb + 16 + l16];
    if (n0 < 512) {
        const int head = nb >> 5;
        bf16* dstb = (head < 8) ? qo : ko;
        const int hm = head & 7;
        const float scl = (head < 8) ? SCALE * LOG2E : 1.0f;
        #pragma unroll
        for (int i = 0; i < 4; i++) {
            const int mlo = m0 + wr * 32 + quad * 4 + i;
            #pragma unroll
            for (int g = 0; g < 2; g++) {
                const int row = mlo + g * 16;
                const float x1 = (g ? c10[i] : c00[i]) + bias0;
                const float x2 = (g ? c11[i] : c01[i]) + bias1;
                const float c = cosb[row * 16 + l16], s = sinb[row * 16 + l16];
                const float r1 = (x1 * c - x2 * s) * scl;
                const float r2 = (x1 * s + x2 * c) * scl;
                const int bb = row >> 11, l = row & 2047;
                bf16* dst = dstb + (((size_t)bb * NHEAD + hm) * SEQ + l) * DHEAD;
                dst[l16] = __float2bfloat16(r1);
                dst[16 + l16] = __float2bfloat16(r2);
            }
        }
    } else {
        const int head = (nb - 512) >> 5;
        const int bb = m0 >> 11;
        const int l0 = (m0 + wr * 32 + quad * 4) & 2047;
        s16x4 p0, p1, p2, p3;
        #pragma unroll
        for (int i = 0; i < 4; i++) {
            p0[i] = bf16_bits(c00[i] + bias0);
            p1[i] = bf16_bits(c10[i] + bias0);
            p2[i] = bf16_bits(c01[i] + bias1);
            p3[i] = bf16_bits(c11[i] + bias1);
        }
        bf16* v0 = vo + (((size_t)bb * NHEAD + head) * DHEAD + l16) * SEQ;
        *(s16x4*)(v0 + l0) = p0;
        *(s16x4*)(v0 + l0 + 16) = p1;
        bf16* v1 = vo + (((size_t)bb * NHEAD + head) * DHEAD + 16 + l16) * SEQ;
        *(s16x4*)(v1 + l0) = p2;
        *(s16x4*)(v1 + l0 + 16) = p3;
    }
}

// ---------------------------------------------------------------------------
// MFMA flash attention (transposed-S, no-max exp2 softmax, split-K 2 halves).
__global__ __launch_bounds__(256) void attn_mfma_kernel(
        const bf16* __restrict__ q, const bf16* __restrict__ k,
        const bf16* __restrict__ v, float* __restrict__ opart,
        float* __restrict__ lsumw) {
    __shared__ __align__(16) bf16 Kt[128 * 40];
    __shared__ __align__(16) bf16 Vt[32 * 136];
    const int tid = threadIdx.x;
    const int wave = tid >> 6, lane = tid & 63;
    const int quad = lane >> 4, l16 = lane & 15;
    const int bh = blockIdx.x >> 6;
    const int qtile = (blockIdx.x >> 1) & 31;
    const int khalf = blockIdx.x & 1;
    const int qbase = qtile * 64 + wave * 16;
    const size_t ql = (size_t)bh * SEQ * DHEAD;
    const size_t vt = (size_t)bh * DHEAD * SEQ;

    const s16x8 bq = *(const s16x8*)(q + ql + (size_t)(qbase + l16) * DHEAD + quad * 8);
    float lsum = 0.f;
    f32x4 o0 = {0.f,0.f,0.f,0.f}, o1 = {0.f,0.f,0.f,0.f};
    const f32x4 zf = {0.f,0.f,0.f,0.f};

    const int tstart = khalf * 1024;
    for (int t0 = tstart; t0 < tstart + 1024; t0 += 128) {
        __syncthreads();
        {
            const int kr = tid >> 2, kc = (tid & 3) * 8;
            *(s16x8*)(Kt + kr * 40 + kc) =
                *(const s16x8*)(k + ql + (size_t)(t0 + kr) * DHEAD + kc);
            *(s16x8*)(Kt + (64 + kr) * 40 + kc) =
                *(const s16x8*)(k + ql + (size_t)(t0 + 64 + kr) * DHEAD + kc);
            const int vd = tid >> 4, vc = (tid & 15) * 8;
            *(s16x8*)(Vt + vd * 136 + vc) =
                *(const s16x8*)(v + vt + (size_t)vd * SEQ + t0 + vc);
            *(s16x8*)(Vt + (16 + vd) * 136 + vc) =
                *(const s16x8*)(v + vt + (size_t)(16 + vd) * SEQ + t0 + vc);
        }
        __syncthreads();
        f32x4 s[8];
        #pragma unroll
        for (int j = 0; j < 8; j++) {
            const s16x8 aK = *(const s16x8*)(Kt + (j * 16 + l16) * 40 + quad * 8);
            s[j] = __builtin_amdgcn_mfma_f32_16x16x32_bf16(aK, bq, zf, 0, 0, 0);
        }
        #pragma unroll
        for (int j = 0; j < 8; j++) {
            float p0 = exp2f(s[j][0]), p1 = exp2f(s[j][1]);
            float p2 = exp2f(s[j][2]), p3 = exp2f(s[j][3]);
            lsum += (p0 + p1) + (p2 + p3);
            s16x4 pa;
            pa[0] = bf16_bits(p0); pa[1] = bf16_bits(p1);
            pa[2] = bf16_bits(p2); pa[3] = bf16_bits(p3);
            const s16x4 bv0 = *(const s16x4*)(Vt + l16 * 136 + j * 16 + quad * 4);
            const s16x4 bv1 = *(const s16x4*)(Vt + (16 + l16) * 136 + j * 16 + quad * 4);
            o0 = __builtin_amdgcn_mfma_f32_16x16x16bf16_1k(pa, bv0, o0, 0, 0, 0);
            o1 = __builtin_amdgcn_mfma_f32_16x16x16bf16_1k(pa, bv1, o1, 0, 0, 0);
        }
    }
    lsum += __shfl_xor(lsum, 16);
    lsum += __shfl_xor(lsum, 32);
    float* op = opart + (size_t)(bh * 2 + khalf) * (SEQ * DHEAD);
    const int qr0 = qbase + quad * 4;
    #pragma unroll
    for (int i = 0; i < 4; i++) {
        op[(qr0 + i) * DHEAD + l16]      = o0[i];
        op[(qr0 + i) * DHEAD + 16 + l16] = o1[i];
    }
    if (quad == 0) lsumw[(bh * 2 + khalf) * SEQ + qbase + l16] = lsum;
}

// ---------------------------------------------------------------------------
// Merge split-K attention partials -> bf16 token-major aob.
__global__ __launch_bounds__(256) void attn_merge_kernel(
        const float* __restrict__ opart, const float* __restrict__ lsumw,
        bf16* __restrict__ aob) {
    const int gid = blockIdx.x * 256 + threadIdx.x;
    const int e = gid * 4;
    const int bh = e >> 16;
    const int rem = e & 65535;
    const int qrow = rem >> 5, d0 = rem & 31;
    const float4 a = *(const float4*)(opart + (size_t)(bh * 2) * 65536 + rem);
    const float4 c = *(const float4*)(opart + (size_t)(bh * 2 + 1) * 65536 + rem);
    const float inv = 1.0f / (lsumw[(bh * 2) * SEQ + qrow] +
                              lsumw[(bh * 2 + 1) * SEQ + qrow]);
    const int b = bh >> 3, h = bh & 7;
    const size_t tok = (size_t)b * SEQ + qrow;
    s16x4 o;
    o[0] = bf16_bits((a.x + c.x) * inv);
    o[1] = bf16_bits((a.y + c.y) * inv);
    o[2] = bf16_bits((a.z + c.z) * inv);
    o[3] = bf16_bits((a.w + c.w) * inv);
    *(s16x4*)(aob + tok * DMODEL + h * DHEAD + d0) = o;
}

// ---------------------------------------------------------------------------
// Pool q projection (exp2 domain) + pack pool biases into pbkv[512].
__global__ __launch_bounds__(256) void pool_qproj_kernel(
        const float* __restrict__ pq, const float* __restrict__ Wq,
        const float* __restrict__ bq, const float* __restrict__ pbk,
        const float* __restrict__ pbv, float* __restrict__ qsb,
        float* __restrict__ pbkv) {
    const int t = threadIdx.x;
    float acc = bq[t];
    for (int kk = 0; kk < DMODEL; kk++) acc += pq[kk] * Wq[kk * DMODEL + t];
    qsb[t] = acc * (SCALE * LOG2E);
    pbkv[t] = pbk[t];
    pbkv[t + 256] = pbv[t];
}

// ---------------------------------------------------------------------------
// Pool partials (exp2 domain): block = (bh, chunk of 128 keys).
__global__ __launch_bounds__(256) void pool_part_kernel(
        const float* __restrict__ qsb, const bf16* __restrict__ pkv,
        float* __restrict__ pws) {
    const int bh = blockIdx.x >> 4, chunk = blockIdx.x & 15;
    const int b = bh >> 3, h = bh & 7;
    const int t = threadIdx.x;
    const int l0 = chunk * 128;
    __shared__ float qsl[32];
    __shared__ float red[256];
    __shared__ float pl[128];
    __shared__ float sog[8][32];
    if (t < 32) qsl[t] = qsb[h * 32 + t];
    __syncthreads();
    const int key = t >> 1, half = t & 1;
    const int l = l0 + key;
    const bf16* kp = pkv + (size_t)(b * SEQ + l) * 512 + h * DHEAD + half * 16;
    const s16x8 k0v = *(const s16x8*)kp;
    const s16x8 k1v = *(const s16x8*)(kp + 8);
    float part = 0.f;
    #pragma unroll
    for (int i = 0; i < 8; i++) {
        part += qsl[half * 16 + i]     * bfb2f(k0v[i]);
        part += qsl[half * 16 + 8 + i] * bfb2f(k1v[i]);
    }
    const float sc = part + __shfl_xor(part, 1);
    const float M = breduce_max(sc, red);
    const float p = exp2f(sc - M);
    const float S = breduce_sum(half == 0 ? p : 0.f, red);
    if (half == 0) pl[key] = p;
    __syncthreads();
    const int d = t & 31, grp = t >> 5;
    float acc = 0.f;
    #pragma unroll
    for (int jj = 0; jj < 16; jj++) {
        const int lk = l0 + grp * 16 + jj;
        acc += pl[grp * 16 + jj] *
               __bfloat162float(pkv[(size_t)(b * SEQ + lk) * 512 + 256 + h * DHEAD + d]);
    }
    sog[grp][d] = acc;
    __syncthreads();
    float* dst = pws + ((size_t)bh * NCHUNK + chunk) * 34;
    if (t < 32) {
        float tot = 0.f;
        #pragma unroll
        for (int g2 = 0; g2 < 8; g2++) tot += sog[g2][t];
        dst[2 + t] = tot;
    } else if (t == 32) dst[0] = M;
    else if (t == 33) dst[1] = S;
}

// ---------------------------------------------------------------------------
// Pool head: merge partials (exp2 domain) + out-proj + LN + LN + ctx proj.
__global__ __launch_bounds__(256) void pool_head_kernel(
        const float* __restrict__ pws, const float* __restrict__ Wo,
        const float* __restrict__ bo, const float* __restrict__ plg,
        const float* __restrict__ plb, const float* __restrict__ clg,
        const float* __restrict__ clb, const float* __restrict__ cW,
        const float* __restrict__ cb, float* __restrict__ out) {
    const int b = blockIdx.x, t = threadIdx.x;
    __shared__ float so[DMODEL], sz[DMODEL], r1[256], r2[256];
    {
        const int h = t >> 5, d = t & 31;
        const float* src = pws + ((size_t)(b * 8 + h) * NCHUNK) * 34;
        float M = -1e30f;
        #pragma unroll
        for (int c = 0; c < NCHUNK; c++) M = fmaxf(M, src[c * 34]);
        float S = 0.f, O = 0.f;
        #pragma unroll
        for (int c = 0; c < NCHUNK; c++) {
            const float w = exp2f(src[c * 34] - M);
            S += w * src[c * 34 + 1];
            O += w * src[c * 34 + 2 + d];
        }
        so[t] = O / S;
    }
    __syncthreads();
    float acc = bo[t];
    for (int kk = 0; kk < DMODEL; kk++) acc += so[kk] * Wo[kk * DMODEL + t];
    float s1, s2;
    breduce_sum2(acc, acc * acc, r1, r2, s1, s2);
    float mu = s1 * (1.0f / DMODEL), var = s2 * (1.0f / DMODEL) - mu * mu;
    const float pooled = (acc - mu) * rsqrtf(var + 1e-5f) * plg[t] + plb[t];
    breduce_sum2(pooled, pooled * pooled, r1, r2, s1, s2);
    mu = s1 * (1.0f / DMODEL); var = s2 * (1.0f / DMODEL) - mu * mu;
    sz[t] = (pooled - mu) * rsqrtf(var + 1e-5f) * clg[t] + clb[t];
    __syncthreads();
    if (t < NCTX) {
        float a = cb[t];
        for (int kk = 0; kk < DMODEL; kk++) a += sz[kk] * cW[kk * NCTX + t];
        out[b * NCTX + t] = a;
    }
}

// ---------------------------------------------------------------------------
extern "C" void kernel_launch(void* const* d_in, const int* in_sizes, int n_in,
                              void* d_out, int out_size, void* d_ws, size_t ws_size,
                              hipStream_t stream) {
    const float* feat  = (const float*)d_in[0];
    const int*   bid   = (const int*)d_in[1];
    const float* emb   = (const float*)d_in[3];
    const float* tokW1 = (const float*)d_in[4];
    const float* tokb1 = (const float*)d_in[5];
    const float* tokW2 = (const float*)d_in[6];
    const float* tokb2 = (const float*)d_in[7];
    const float* ln1g  = (const float*)d_in[8];
    const float* ln1b  = (const float*)d_in[9];
    const float* Wqkv  = (const float*)d_in[10];
    const float* bqkv  = (const float*)d_in[11];
    const float* Wout  = (const float*)d_in[12];
    const float* bout  = (const float*)d_in[13];
    const float* ln2g  = (const float*)d_in[14];
    const float* ln2b  = (const float*)d_in[15];
    const float* fW1   = (const float*)d_in[16];
    const float* fb1   = (const float*)d_in[17];
    const float* fW2   = (const float*)d_in[18];
    const float* fb2   = (const float*)d_in[19];
    const float* fng   = (const float*)d_in[20];
    const float* fnb   = (const float*)d_in[21];
    const float* pq    = (const float*)d_in[22];
    const float* pWq   = (const float*)d_in[23];
    const float* pWk   = (const float*)d_in[24];
    const float* pWv   = (const float*)d_in[25];
    const float* pbq   = (const float*)d_in[26];
    const float* pbk   = (const float*)d_in[27];
    const float* pbv   = (const float*)d_in[28];
    const float* pWo   = (const float*)d_in[29];
    const float* pbo   = (const float*)d_in[30];
    const float* plg   = (const float*)d_in[31];
    const float* plb   = (const float*)d_in[32];
    const float* clg   = (const float*)d_in[33];
    const float* clb   = (const float*)d_in[34];
    const float* cW    = (const float*)d_in[35];
    const float* cb    = (const float*)d_in[36];
    float* out = (float*)d_out;

    // ---- workspace layout ----
    float* xb    = (float*)d_ws;             // 1,048,576 f
    float* cosb  = xb + 1048576;             // 65,536 f
    float* sinb  = cosb + 65536;             // 65,536 f
    float* opart = sinb + 65536;             // 2,097,152 f (8 MB)
    float* lsumw = opart + 2097152;          // 65,536 f
    float* pws   = lsumw + 65536;            // 8,704 f
    float* qsb   = pws + 8704;               // 256 f
    float* pbkv  = qsb + 256;                // 512 f
    bf16* ybf    = (bf16*)(pbkv + 512);      // 1,048,576 bf16
    bf16* qb     = ybf + 1048576;            // 1,048,576 bf16
    bf16* kb     = qb + 1048576;             // 1,048,576 bf16
    bf16* vb     = kb + 1048576;             // 1,048,576 bf16
    bf16* aob    = vb + 1048576;             // 1,048,576 bf16
    bf16* hb     = (bf16*)opart;             // FFN hidden aliases opart (8 MB)
    bf16* h8     = (bf16*)opart;             // tok hidden (pre-layers)
    bf16* pkv    = (bf16*)opart;             // pool K|V (4096x512) post-layers
    bf16* WTq    = aob + 1048576;            // 1,179,648 bf16
    bf16* WTo    = WTq + 1179648;            //   393,216 bf16
    bf16* WT1    = WTo + 393216;             // 1,572,864 bf16
    bf16* WT2    = WT1 + 1572864;            // 1,572,864 bf16
    bf16* WTpk   = WT2 + 1572864;            //    65,536 bf16 (contiguous with
    bf16* WTpv   = WTpk + 65536;             //    65,536 bf16  WTpv: 512x256)
    bf16* WTt2   = WTpv + 65536;             //    65,536 bf16

    // ---- weight convert/transpose (single launch) ----
    wt_all_kernel<<<4800, 256, 0, stream>>>(Wqkv, Wout, fW1, fW2, pWk, pWv, tokW2,
                                            WTq, WTo, WT1, WT2, WTpk, WTpv, WTt2);

    // ---- token embed ----
    tok_hid_kernel<<<NROWS / 4, 256, 0, stream>>>(feat, bid, emb, tokW1, tokb1,
                                                  h8, cosb, sinb);
    gemm64_kernel<3><<<dim3(64, 4), 256, 0, stream>>>(h8, WTt2, tokb2, xb, 256, 256);

    for (int i = 0; i < NLAYER; i++) {
        ln_bf16_kernel<<<NROWS / 4, 256, 0, stream>>>(
            xb, ln1g + i * DMODEL, ln1b + i * DMODEL, ybf);
        gemm_qkv_kernel<<<dim3(64, 12), 256, 0, stream>>>(
            ybf, WTq + (size_t)i * 196608, bqkv + i * 768, cosb, sinb, qb, kb, vb);
        attn_mfma_kernel<<<1024, 256, 0, stream>>>(qb, kb, vb, opart, lsumw);
        attn_merge_kernel<<<1024, 256, 0, stream>>>(opart, lsumw, aob);
        gemm64_kernel<1><<<dim3(64, 4), 256, 0, stream>>>(
            aob, WTo + (size_t)i * 65536, bout + i * DMODEL, xb, 256, 256);
        ln_bf16_kernel<<<NROWS / 4, 256, 0, stream>>>(
            xb, ln2g + i * DMODEL, ln2b + i * DMODEL, ybf);
        gemm64_kernel<2><<<dim3(64, 16), 256, 0, stream>>>(
            ybf, WT1 + (size_t)i * 262144, fb1 + i * DFF, hb, 256, 1024);
        gemm64_kernel<1><<<dim3(64, 4), 256, 0, stream>>>(
            hb, WT2 + (size_t)i * 262144, fb2 + i * DMODEL, xb, 1024, 256);
    }
    // final LN + pooling (K and V projections in ONE N=512 GEMM)
    ln_bf16_kernel<<<NROWS / 4, 256, 0, stream>>>(xb, fng, fnb, ybf);
    pool_qproj_kernel<<<1, 256, 0, stream>>>(pq, pWq, pbq, pbk, pbv, qsb, pbkv);
    gemm64_kernel<0><<<dim3(64, 8), 256, 0, stream>>>(ybf, WTpk, pbkv, pkv, 256, 512);
    pool_part_kernel<<<16 * NCHUNK, 256, 0, stream>>>(qsb, pkv, pws);
    pool_head_kernel<<<NBATCH, 256, 0, stream>>>(pws, pWo, pbo, plg, plb,
                                                 clg, clb, cW, cb, out);
}

// Round 13
// 585.590 us; speedup vs baseline: 1.0675x; 1.0675x over previous
//
#include <hip/hip_runtime.h>
#include <hip/hip_bf16.h>

// Round 13: R12 with exp2f -> __builtin_amdgcn_exp2f (raw v_exp_f32; HIP's
// exp2f lowers to precise OCML which regressed R12). Log2-domain softmax kept
// (q pre-scaled by SCALE*log2e in the RoPE epilogue — free).

#define NLAYER 6
#define DMODEL 256
#define NHEAD  8
#define DHEAD  32
#define DFF    1024
#define NCTX   64
#define NBATCH 2
#define SEQ    2048
#define NROWS  (NBATCH*SEQ)          // 4096
#define SCALE  0.17677669529663687f  // 1/sqrt(32)
#define LOG2E  1.4426950408889634f
#define NCHUNK 16

typedef short s16x8 __attribute__((ext_vector_type(8)));
typedef short s16x4 __attribute__((ext_vector_type(4)));
typedef float f32x4 __attribute__((ext_vector_type(4)));
using bf16 = __hip_bfloat16;

__device__ __forceinline__ float fast_exp2(float x) {
    return __builtin_amdgcn_exp2f(x);   // raw v_exp_f32
}
__device__ __forceinline__ float gelu_exact(float x) {
    return 0.5f * x * (1.0f + erff(x * 0.7071067811865475f));
}
__device__ __forceinline__ short bf16_bits(float x) {
    bf16 h = __float2bfloat16(x);
    return *(short*)&h;
}
__device__ __forceinline__ float bfb2f(short s) {
    return __uint_as_float(((unsigned)(unsigned short)s) << 16);
}
__device__ __forceinline__ void load16_lds(const void* g, void* l) {
    __builtin_amdgcn_global_load_lds(
        (const __attribute__((address_space(1))) void*)g,
        (__attribute__((address_space(3))) void*)l, 16, 0, 0);
}

__device__ __forceinline__ void breduce_sum2(float v1, float v2, float* r1, float* r2,
                                             float& o1, float& o2) {
    const int t = threadIdx.x;
    r1[t] = v1; r2[t] = v2;
    __syncthreads();
    for (int s = 128; s > 0; s >>= 1) {
        if (t < s) { r1[t] += r1[t + s]; r2[t] += r2[t + s]; }
        __syncthreads();
    }
    o1 = r1[0]; o2 = r2[0];
    __syncthreads();
}
__device__ __forceinline__ float breduce_max(float v, float* r1) {
    const int t = threadIdx.x;
    r1[t] = v; __syncthreads();
    for (int s = 128; s > 0; s >>= 1) {
        if (t < s) r1[t] = fmaxf(r1[t], r1[t + s]);
        __syncthreads();
    }
    float res = r1[0]; __syncthreads();
    return res;
}
__device__ __forceinline__ float breduce_sum(float v, float* r1) {
    const int t = threadIdx.x;
    r1[t] = v; __syncthreads();
    for (int s = 128; s > 0; s >>= 1) {
        if (t < s) r1[t] += r1[t + s];
        __syncthreads();
    }
    float res = r1[0]; __syncthreads();
    return res;
}

// ---------------------------------------------------------------------------
// All weight transposes in one launch. W (K x N fp32) -> WT (N x K bf16).
__global__ __launch_bounds__(256) void wt_all_kernel(
        const float* __restrict__ Wqkv, const float* __restrict__ Wout,
        const float* __restrict__ fW1, const float* __restrict__ fW2,
        const float* __restrict__ pWk, const float* __restrict__ pWv,
        const float* __restrict__ tokW2,
        bf16* __restrict__ WTq, bf16* __restrict__ WTo, bf16* __restrict__ WT1,
        bf16* __restrict__ WT2, bf16* __restrict__ WTpk, bf16* __restrict__ WTpv,
        bf16* __restrict__ WTt2) {
    int bid = blockIdx.x;
    const float* W; bf16* WT; int K, N, kt;
    if (bid < 1152)      { W = Wqkv;  WT = WTq;  K = 256;  N = 768;  kt = 8;  }
    else if (bid < 1536) { W = Wout;  WT = WTo;  K = 256;  N = 256;  kt = 8;  bid -= 1152; }
    else if (bid < 3072) { W = fW1;   WT = WT1;  K = 256;  N = 1024; kt = 8;  bid -= 1536; }
    else if (bid < 4608) { W = fW2;   WT = WT2;  K = 1024; N = 256;  kt = 32; bid -= 3072; }
    else if (bid < 4672) { W = pWk;   WT = WTpk; K = 256;  N = 256;  kt = 8;  bid -= 4608; }
    else if (bid < 4736) { W = pWv;   WT = WTpv; K = 256;  N = 256;  kt = 8;  bid -= 4672; }
    else                 { W = tokW2; WT = WTt2; K = 256;  N = 256;  kt = 8;  bid -= 4736; }
    const int per = kt * (N >> 5);
    const int zz = bid / per;
    const int rel = bid % per;
    const int k0 = (rel % kt) * 32, n0 = (rel / kt) * 32;
    W  += (size_t)zz * K * N;
    WT += (size_t)zz * K * N;
    __shared__ float tile[32][33];
    const int tx = threadIdx.x & 31, ty = threadIdx.x >> 5;
    #pragma unroll
    for (int i = 0; i < 32; i += 8)
        tile[ty + i][tx] = W[(size_t)(k0 + ty + i) * N + n0 + tx];
    __syncthreads();
    #pragma unroll
    for (int i = 0; i < 32; i += 8)
        WT[(size_t)(n0 + ty + i) * K + k0 + tx] = __float2bfloat16(tile[tx][ty + i]);
}

// ---------------------------------------------------------------------------
__global__ __launch_bounds__(256) void tok_hid_kernel(
        const float* __restrict__ feat, const int* __restrict__ bid,
        const float* __restrict__ emb, const float* __restrict__ W1,
        const float* __restrict__ b1, bf16* __restrict__ h8,
        float* __restrict__ cosb, float* __restrict__ sinb) {
    const int row0 = blockIdx.x * 4;
    const int t = threadIdx.x;
    __shared__ float tok[4][14];
    if (t < 56) {
        const int r = t / 14, i = t % 14;
        const int row = row0 + r;
        tok[r][i] = (i < 6) ? feat[row * 6 + i] : emb[bid[row] * 8 + (i - 6)];
    }
    if (t < 64) {
        const int r = t >> 4, i = t & 15;
        const int row = row0 + r;
        const float pos = feat[row * 6] * 512.0f;
        const float invf = expf(-9.210340371976184f * (float)i * (1.0f / 16.0f));
        const float fr = pos * invf;
        cosb[row * 16 + i] = cosf(fr);
        sinb[row * 16 + i] = sinf(fr);
    }
    __syncthreads();
    float w[14];
    #pragma unroll
    for (int k2 = 0; k2 < 14; k2++) w[k2] = W1[k2 * DMODEL + t];
    const float bb = b1[t];
    #pragma unroll
    for (int r = 0; r < 4; r++) {
        float acc = bb;
        #pragma unroll
        for (int k2 = 0; k2 < 14; k2++) acc += tok[r][k2] * w[k2];
        h8[(size_t)(row0 + r) * DMODEL + t] = __float2bfloat16(gelu_exact(acc));
    }
}

// ---------------------------------------------------------------------------
__global__ __launch_bounds__(256) void ln_bf16_kernel(
        const float* __restrict__ x, const float* __restrict__ g,
        const float* __restrict__ b, bf16* __restrict__ y) {
    const int wave = threadIdx.x >> 6, lane = threadIdx.x & 63;
    const int row = blockIdx.x * 4 + wave;
    const float4 xv = *(const float4*)(x + (size_t)row * DMODEL + lane * 4);
    float s1 = xv.x + xv.y + xv.z + xv.w;
    float s2 = xv.x * xv.x + xv.y * xv.y + xv.z * xv.z + xv.w * xv.w;
    #pragma unroll
    for (int off = 32; off >= 1; off >>= 1) {
        s1 += __shfl_xor(s1, off);
        s2 += __shfl_xor(s2, off);
    }
    const float mu = s1 * (1.0f / DMODEL);
    const float var = s2 * (1.0f / DMODEL) - mu * mu;
    const float rstd = rsqrtf(var + 1e-5f);
    const float4 gv = *(const float4*)(g + lane * 4);
    const float4 bv = *(const float4*)(b + lane * 4);
    s16x4 o;
    o.x = bf16_bits((xv.x - mu) * rstd * gv.x + bv.x);
    o.y = bf16_bits((xv.y - mu) * rstd * gv.y + bv.y);
    o.z = bf16_bits((xv.z - mu) * rstd * gv.z + bv.z);
    o.w = bf16_bits((xv.w - mu) * rstd * gv.w + bv.w);
    *(s16x4*)(y + (size_t)row * DMODEL + lane * 4) = o;
}

// ---------------------------------------------------------------------------
// Generic MFMA GEMM. MODE 0: bf16; 1: += fp32; 2: gelu->bf16; 3: fp32.
template<int MODE>
__global__ __launch_bounds__(256) void gemm64_kernel(
        const bf16* __restrict__ A, const bf16* __restrict__ WT,
        const float* __restrict__ bias, void* __restrict__ out,
        int K, int ldc) {
    __shared__ __align__(16) bf16 As[64 * 64];
    __shared__ __align__(16) bf16 Ws[64 * 64];
    const int tid = threadIdx.x;
    const int lane = tid & 63, wave = tid >> 6;
    const int quad = lane >> 4, l16 = lane & 15;
    const int wr = wave >> 1, wc = wave & 1;
    const int m0 = blockIdx.x * 64, n0 = blockIdx.y * 64;
    const int cg = lane & 7;
    const int r0s = wave * 16 + (lane >> 3);
    f32x4 c00 = {0.f,0.f,0.f,0.f}, c01 = {0.f,0.f,0.f,0.f};
    f32x4 c10 = {0.f,0.f,0.f,0.f}, c11 = {0.f,0.f,0.f,0.f};

    for (int k0 = 0; k0 < K; k0 += 64) {
        __syncthreads();
        #pragma unroll
        for (int j = 0; j < 2; j++) {
            const int r = r0s + j * 8;
            const int kg = cg ^ (r & 7);
            load16_lds(A  + (size_t)(m0 + r) * K + k0 + kg * 8,
                       As + wave * 1024 + j * 512);
            load16_lds(WT + (size_t)(n0 + r) * K + k0 + kg * 8,
                       Ws + wave * 1024 + j * 512);
        }
        __syncthreads();
        #pragma unroll
        for (int kk = 0; kk < 64; kk += 32) {
            const int kg = (kk >> 3) + quad;
            const int ra0 = wr * 32 + l16, ra1 = ra0 + 16;
            const int rb0 = wc * 32 + l16, rb1 = rb0 + 16;
            const s16x8 a0 = *(const s16x8*)(As + ra0 * 64 + ((kg ^ (ra0 & 7)) << 3));
            const s16x8 a1 = *(const s16x8*)(As + ra1 * 64 + ((kg ^ (ra1 & 7)) << 3));
            const s16x8 b0 = *(const s16x8*)(Ws + rb0 * 64 + ((kg ^ (rb0 & 7)) << 3));
            const s16x8 b1 = *(const s16x8*)(Ws + rb1 * 64 + ((kg ^ (rb1 & 7)) << 3));
            c00 = __builtin_amdgcn_mfma_f32_16x16x32_bf16(a0, b0, c00, 0, 0, 0);
            c01 = __builtin_amdgcn_mfma_f32_16x16x32_bf16(a0, b1, c01, 0, 0, 0);
            c10 = __builtin_amdgcn_mfma_f32_16x16x32_bf16(a1, b0, c10, 0, 0, 0);
            c11 = __builtin_amdgcn_mfma_f32_16x16x32_bf16(a1, b1, c11, 0, 0, 0);
        }
    }
    const int nb = n0 + wc * 32;
    const float bias0 = bias[nb + l16], bias1 = bias[nb + 16 + l16];
    #pragma unroll
    for (int i = 0; i < 4; i++) {
        const int mlo = m0 + wr * 32 + quad * 4 + i;
        const int mhi = mlo + 16;
        const float v00 = c00[i] + bias0, v01 = c01[i] + bias1;
        const float v10 = c10[i] + bias0, v11 = c11[i] + bias1;
        if (MODE == 1) {
            float* C = (float*)out;
            C[(size_t)mlo * ldc + nb + l16]      += v00;
            C[(size_t)mlo * ldc + nb + 16 + l16] += v01;
            C[(size_t)mhi * ldc + nb + l16]      += v10;
            C[(size_t)mhi * ldc + nb + 16 + l16] += v11;
        } else if (MODE == 3) {
            float* C = (float*)out;
            C[(size_t)mlo * ldc + nb + l16]      = v00;
            C[(size_t)mlo * ldc + nb + 16 + l16] = v01;
            C[(size_t)mhi * ldc + nb + l16]      = v10;
            C[(size_t)mhi * ldc + nb + 16 + l16] = v11;
        } else if (MODE == 0) {
            bf16* C = (bf16*)out;
            C[(size_t)mlo * ldc + nb + l16]      = __float2bfloat16(v00);
            C[(size_t)mlo * ldc + nb + 16 + l16] = __float2bfloat16(v01);
            C[(size_t)mhi * ldc + nb + l16]      = __float2bfloat16(v10);
            C[(size_t)mhi * ldc + nb + 16 + l16] = __float2bfloat16(v11);
        } else {
            bf16* C = (bf16*)out;
            C[(size_t)mlo * ldc + nb + l16]      = __float2bfloat16(gelu_exact(v00));
            C[(size_t)mlo * ldc + nb + 16 + l16] = __float2bfloat16(gelu_exact(v01));
            C[(size_t)mhi * ldc + nb + l16]      = __float2bfloat16(gelu_exact(v10));
            C[(size_t)mhi * ldc + nb + 16 + l16] = __float2bfloat16(gelu_exact(v11));
        }
    }
}

// ---------------------------------------------------------------------------
// QKV GEMM with fused RoPE epilogue + direct v^T store. Grid (64, 12).
// q is pre-scaled by SCALE*LOG2E (exp2-domain softmax downstream).
__global__ __launch_bounds__(256) void gemm_qkv_kernel(
        const bf16* __restrict__ A, const bf16* __restrict__ WT,
        const float* __restrict__ bias, const float* __restrict__ cosb,
        const float* __restrict__ sinb, bf16* __restrict__ qo,
        bf16* __restrict__ ko, bf16* __restrict__ vo) {
    __shared__ __align__(16) bf16 As[64 * 64];
    __shared__ __align__(16) bf16 Ws[64 * 64];
    const int tid = threadIdx.x;
    const int lane = tid & 63, wave = tid >> 6;
    const int quad = lane >> 4, l16 = lane & 15;
    const int wr = wave >> 1, wc = wave & 1;
    const int m0 = blockIdx.x * 64, n0 = blockIdx.y * 64;
    const int cg = lane & 7;
    const int r0s = wave * 16 + (lane >> 3);
    f32x4 c00 = {0.f,0.f,0.f,0.f}, c01 = {0.f,0.f,0.f,0.f};
    f32x4 c10 = {0.f,0.f,0.f,0.f}, c11 = {0.f,0.f,0.f,0.f};
    const int K = DMODEL;

    for (int k0 = 0; k0 < K; k0 += 64) {
        __syncthreads();
        #pragma unroll
        for (int j = 0; j < 2; j++) {
            const int r = r0s + j * 8;
            const int kg = cg ^ (r & 7);
            load16_lds(A  + (size_t)(m0 + r) * K + k0 + kg * 8,
                       As + wave * 1024 + j * 512);
            load16_lds(WT + (size_t)(n0 + r) * K + k0 + kg * 8,
                       Ws + wave * 1024 + j * 512);
        }
        __syncthreads();
        #pragma unroll
        for (int kk = 0; kk < 64; kk += 32) {
            const int kg = (kk >> 3) + quad;
            const int ra0 = wr * 32 + l16, ra1 = ra0 + 16;
            const int rb0 = wc * 32 + l16, rb1 = rb0 + 16;
            const s16x8 a0 = *(const s16x8*)(As + ra0 * 64 + ((kg ^ (ra0 & 7)) << 3));
            const s16x8 a1 = *(const s16x8*)(As + ra1 * 64 + ((kg ^ (ra1 & 7)) << 3));
            const s16x8 b0 = *(const s16x8*)(Ws + rb0 * 64 + ((kg ^ (rb0 & 7)) << 3));
            const s16x8 b1 = *(const s16x8*)(Ws + rb1 * 64 + ((kg ^ (rb1 & 7)) << 3));
            c00 = __builtin_amdgcn_mfma_f32_16x16x32_bf16(a0, b0, c00, 0, 0, 0);
            c01 = __builtin_amdgcn_mfma_f32_16x16x32_bf16(a0, b1, c01, 0, 0, 0);
            c10 = __builtin_amdgcn_mfma_f32_16x16x32_bf16(a1, b0, c10, 0, 0, 0);
            c11 = __builtin_amdgcn_mfma_f32_16x16x32_bf16(a1, b1, c11, 0, 0, 0);
        }
    }
    const int nb = n0 + wc * 32;
    const float bias0 = bias[nb + l16], bias1 = bias[nb + 16 + l16];
    if (n0 < 512) {
        const int head = nb >> 5;
        bf16* dstb = (head < 8) ? qo : ko;
        const int hm = head & 7;
        const float scl = (head < 8) ? SCALE * LOG2E : 1.0f;
        #pragma unroll
        for (int i = 0; i < 4; i++) {
            const int mlo = m0 + wr * 32 + quad * 4 + i;
            #pragma unroll
            for (int g = 0; g < 2; g++) {
                const int row = mlo + g * 16;
                const float x1 = (g ? c10[i] : c00[i]) + bias0;
                const float x2 = (g ? c11[i] : c01[i]) + bias1;
                const float c = cosb[row * 16 + l16], s = sinb[row * 16 + l16];
                const float r1 = (x1 * c - x2 * s) * scl;
                const float r2 = (x1 * s + x2 * c) * scl;
                const int bb = row >> 11, l = row & 2047;
                bf16* dst = dstb + (((size_t)bb * NHEAD + hm) * SEQ + l) * DHEAD;
                dst[l16] = __float2bfloat16(r1);
                dst[16 + l16] = __float2bfloat16(r2);
            }
        }
    } else {
        const int head = (nb - 512) >> 5;
        const int bb = m0 >> 11;
        const int l0 = (m0 + wr * 32 + quad * 4) & 2047;
        s16x4 p0, p1, p2, p3;
        #pragma unroll
        for (int i = 0; i < 4; i++) {
            p0[i] = bf16_bits(c00[i] + bias0);
            p1[i] = bf16_bits(c10[i] + bias0);
            p2[i] = bf16_bits(c01[i] + bias1);
            p3[i] = bf16_bits(c11[i] + bias1);
        }
        bf16* v0 = vo + (((size_t)bb * NHEAD + head) * DHEAD + l16) * SEQ;
        *(s16x4*)(v0 + l0) = p0;
        *(s16x4*)(v0 + l0 + 16) = p1;
        bf16* v1 = vo + (((size_t)bb * NHEAD + head) * DHEAD + 16 + l16) * SEQ;
        *(s16x4*)(v1 + l0) = p2;
        *(s16x4*)(v1 + l0 + 16) = p3;
    }
}

// ---------------------------------------------------------------------------
// MFMA flash attention (transposed-S, no-max exp2 softmax, split-K 2 halves).
__global__ __launch_bounds__(256) void attn_mfma_kernel(
        const bf16* __restrict__ q, const bf16* __restrict__ k,
        const bf16* __restrict__ v, float* __restrict__ opart,
        float* __restrict__ lsumw) {
    __shared__ __align__(16) bf16 Kt[128 * 40];
    __shared__ __align__(16) bf16 Vt[32 * 136];
    const int tid = threadIdx.x;
    const int wave = tid >> 6, lane = tid & 63;
    const int quad = lane >> 4, l16 = lane & 15;
    const int bh = blockIdx.x >> 6;
    const int qtile = (blockIdx.x >> 1) & 31;
    const int khalf = blockIdx.x & 1;
    const int qbase = qtile * 64 + wave * 16;
    const size_t ql = (size_t)bh * SEQ * DHEAD;
    const size_t vt = (size_t)bh * DHEAD * SEQ;

    const s16x8 bq = *(const s16x8*)(q + ql + (size_t)(qbase + l16) * DHEAD + quad * 8);
    float lsum = 0.f;
    f32x4 o0 = {0.f,0.f,0.f,0.f}, o1 = {0.f,0.f,0.f,0.f};
    const f32x4 zf = {0.f,0.f,0.f,0.f};

    const int tstart = khalf * 1024;
    for (int t0 = tstart; t0 < tstart + 1024; t0 += 128) {
        __syncthreads();
        {
            const int kr = tid >> 2, kc = (tid & 3) * 8;
            *(s16x8*)(Kt + kr * 40 + kc) =
                *(const s16x8*)(k + ql + (size_t)(t0 + kr) * DHEAD + kc);
            *(s16x8*)(Kt + (64 + kr) * 40 + kc) =
                *(const s16x8*)(k + ql + (size_t)(t0 + 64 + kr) * DHEAD + kc);
            const int vd = tid >> 4, vc = (tid & 15) * 8;
            *(s16x8*)(Vt + vd * 136 + vc) =
                *(const s16x8*)(v + vt + (size_t)vd * SEQ + t0 + vc);
            *(s16x8*)(Vt + (16 + vd) * 136 + vc) =
                *(const s16x8*)(v + vt + (size_t)(16 + vd) * SEQ + t0 + vc);
        }
        __syncthreads();
        f32x4 s[8];
        #pragma unroll
        for (int j = 0; j < 8; j++) {
            const s16x8 aK = *(const s16x8*)(Kt + (j * 16 + l16) * 40 + quad * 8);
            s[j] = __builtin_amdgcn_mfma_f32_16x16x32_bf16(aK, bq, zf, 0, 0, 0);
        }
        #pragma unroll
        for (int j = 0; j < 8; j++) {
            float p0 = fast_exp2(s[j][0]), p1 = fast_exp2(s[j][1]);
            float p2 = fast_exp2(s[j][2]), p3 = fast_exp2(s[j][3]);
            lsum += (p0 + p1) + (p2 + p3);
            s16x4 pa;
            pa[0] = bf16_bits(p0); pa[1] = bf16_bits(p1);
            pa[2] = bf16_bits(p2); pa[3] = bf16_bits(p3);
            const s16x4 bv0 = *(const s16x4*)(Vt + l16 * 136 + j * 16 + quad * 4);
            const s16x4 bv1 = *(const s16x4*)(Vt + (16 + l16) * 136 + j * 16 + quad * 4);
            o0 = __builtin_amdgcn_mfma_f32_16x16x16bf16_1k(pa, bv0, o0, 0, 0, 0);
            o1 = __builtin_amdgcn_mfma_f32_16x16x16bf16_1k(pa, bv1, o1, 0, 0, 0);
        }
    }
    lsum += __shfl_xor(lsum, 16);
    lsum += __shfl_xor(lsum, 32);
    float* op = opart + (size_t)(bh * 2 + khalf) * (SEQ * DHEAD);
    const int qr0 = qbase + quad * 4;
    #pragma unroll
    for (int i = 0; i < 4; i++) {
        op[(qr0 + i) * DHEAD + l16]      = o0[i];
        op[(qr0 + i) * DHEAD + 16 + l16] = o1[i];
    }
    if (quad == 0) lsumw[(bh * 2 + khalf) * SEQ + qbase + l16] = lsum;
}

// ---------------------------------------------------------------------------
// Merge split-K attention partials -> bf16 token-major aob.
__global__ __launch_bounds__(256) void attn_merge_kernel(
        const float* __restrict__ opart, const float* __restrict__ lsumw,
        bf16* __restrict__ aob) {
    const int gid = blockIdx.x * 256 + threadIdx.x;
    const int e = gid * 4;
    const int bh = e >> 16;
    const int rem = e & 65535;
    const int qrow = rem >> 5, d0 = rem & 31;
    const float4 a = *(const float4*)(opart + (size_t)(bh * 2) * 65536 + rem);
    const float4 c = *(const float4*)(opart + (size_t)(bh * 2 + 1) * 65536 + rem);
    const float inv = 1.0f / (lsumw[(bh * 2) * SEQ + qrow] +
                              lsumw[(bh * 2 + 1) * SEQ + qrow]);
    const int b = bh >> 3, h = bh & 7;
    const size_t tok = (size_t)b * SEQ + qrow;
    s16x4 o;
    o[0] = bf16_bits((a.x + c.x) * inv);
    o[1] = bf16_bits((a.y + c.y) * inv);
    o[2] = bf16_bits((a.z + c.z) * inv);
    o[3] = bf16_bits((a.w + c.w) * inv);
    *(s16x4*)(aob + tok * DMODEL + h * DHEAD + d0) = o;
}

// ---------------------------------------------------------------------------
// Pool q projection (exp2 domain) + pack pool biases into pbkv[512].
__global__ __launch_bounds__(256) void pool_qproj_kernel(
        const float* __restrict__ pq, const float* __restrict__ Wq,
        const float* __restrict__ bq, const float* __restrict__ pbk,
        const float* __restrict__ pbv, float* __restrict__ qsb,
        float* __restrict__ pbkv) {
    const int t = threadIdx.x;
    float acc = bq[t];
    for (int kk = 0; kk < DMODEL; kk++) acc += pq[kk] * Wq[kk * DMODEL + t];
    qsb[t] = acc * (SCALE * LOG2E);
    pbkv[t] = pbk[t];
    pbkv[t + 256] = pbv[t];
}

// ---------------------------------------------------------------------------
// Pool partials (exp2 domain): block = (bh, chunk of 128 keys).
__global__ __launch_bounds__(256) void pool_part_kernel(
        const float* __restrict__ qsb, const bf16* __restrict__ pkv,
        float* __restrict__ pws) {
    const int bh = blockIdx.x >> 4, chunk = blockIdx.x & 15;
    const int b = bh >> 3, h = bh & 7;
    const int t = threadIdx.x;
    const int l0 = chunk * 128;
    __shared__ float qsl[32];
    __shared__ float red[256];
    __shared__ float pl[128];
    __shared__ float sog[8][32];
    if (t < 32) qsl[t] = qsb[h * 32 + t];
    __syncthreads();
    const int key = t >> 1, half = t & 1;
    const int l = l0 + key;
    const bf16* kp = pkv + (size_t)(b * SEQ + l) * 512 + h * DHEAD + half * 16;
    const s16x8 k0v = *(const s16x8*)kp;
    const s16x8 k1v = *(const s16x8*)(kp + 8);
    float part = 0.f;
    #pragma unroll
    for (int i = 0; i < 8; i++) {
        part += qsl[half * 16 + i]     * bfb2f(k0v[i]);
        part += qsl[half * 16 + 8 + i] * bfb2f(k1v[i]);
    }
    const float sc = part + __shfl_xor(part, 1);
    const float M = breduce_max(sc, red);
    const float p = fast_exp2(sc - M);
    const float S = breduce_sum(half == 0 ? p : 0.f, red);
    if (half == 0) pl[key] = p;
    __syncthreads();
    const int d = t & 31, grp = t >> 5;
    float acc = 0.f;
    #pragma unroll
    for (int jj = 0; jj < 16; jj++) {
        const int lk = l0 + grp * 16 + jj;
        acc += pl[grp * 16 + jj] *
               __bfloat162float(pkv[(size_t)(b * SEQ + lk) * 512 + 256 + h * DHEAD + d]);
    }
    sog[grp][d] = acc;
    __syncthreads();
    float* dst = pws + ((size_t)bh * NCHUNK + chunk) * 34;
    if (t < 32) {
        float tot = 0.f;
        #pragma unroll
        for (int g2 = 0; g2 < 8; g2++) tot += sog[g2][t];
        dst[2 + t] = tot;
    } else if (t == 32) dst[0] = M;
    else if (t == 33) dst[1] = S;
}

// ---------------------------------------------------------------------------
// Pool head: merge partials (exp2 domain) + out-proj + LN + LN + ctx proj.
__global__ __launch_bounds__(256) void pool_head_kernel(
        const float* __restrict__ pws, const float* __restrict__ Wo,
        const float* __restrict__ bo, const float* __restrict__ plg,
        const float* __restrict__ plb, const float* __restrict__ clg,
        const float* __restrict__ clb, const float* __restrict__ cW,
        const float* __restrict__ cb, float* __restrict__ out) {
    const int b = blockIdx.x, t = threadIdx.x;
    __shared__ float so[DMODEL], sz[DMODEL], r1[256], r2[256];
    {
        const int h = t >> 5, d = t & 31;
        const float* src = pws + ((size_t)(b * 8 + h) * NCHUNK) * 34;
        float M = -1e30f;
        #pragma unroll
        for (int c = 0; c < NCHUNK; c++) M = fmaxf(M, src[c * 34]);
        float S = 0.f, O = 0.f;
        #pragma unroll
        for (int c = 0; c < NCHUNK; c++) {
            const float w = fast_exp2(src[c * 34] - M);
            S += w * src[c * 34 + 1];
            O += w * src[c * 34 + 2 + d];
        }
        so[t] = O / S;
    }
    __syncthreads();
    float acc = bo[t];
    for (int kk = 0; kk < DMODEL; kk++) acc += so[kk] * Wo[kk * DMODEL + t];
    float s1, s2;
    breduce_sum2(acc, acc * acc, r1, r2, s1, s2);
    float mu = s1 * (1.0f / DMODEL), var = s2 * (1.0f / DMODEL) - mu * mu;
    const float pooled = (acc - mu) * rsqrtf(var + 1e-5f) * plg[t] + plb[t];
    breduce_sum2(pooled, pooled * pooled, r1, r2, s1, s2);
    mu = s1 * (1.0f / DMODEL); var = s2 * (1.0f / DMODEL) - mu * mu;
    sz[t] = (pooled - mu) * rsqrtf(var + 1e-5f) * clg[t] + clb[t];
    __syncthreads();
    if (t < NCTX) {
        float a = cb[t];
        for (int kk = 0; kk < DMODEL; kk++) a += sz[kk] * cW[kk * NCTX + t];
        out[b * NCTX + t] = a;
    }
}

// ---------------------------------------------------------------------------
extern "C" void kernel_launch(void* const* d_in, const int* in_sizes, int n_in,
                              void* d_out, int out_size, void* d_ws, size_t ws_size,
                              hipStream_t stream) {
    const float* feat  = (const float*)d_in[0];
    const int*   bid   = (const int*)d_in[1];
    const float* emb   = (const float*)d_in[3];
    const float* tokW1 = (const float*)d_in[4];
    const float* tokb1 = (const float*)d_in[5];
    const float* tokW2 = (const float*)d_in[6];
    const float* tokb2 = (const float*)d_in[7];
    const float* ln1g  = (const float*)d_in[8];
    const float* ln1b  = (const float*)d_in[9];
    const float* Wqkv  = (const float*)d_in[10];
    const float* bqkv  = (const float*)d_in[11];
    const float* Wout  = (const float*)d_in[12];
    const float* bout  = (const float*)d_in[13];
    const float* ln2g  = (const float*)d_in[14];
    const float* ln2b  = (const float*)d_in[15];
    const float* fW1   = (const float*)d_in[16];
    const float* fb1   = (const float*)d_in[17];
    const float* fW2   = (const float*)d_in[18];
    const float* fb2   = (const float*)d_in[19];
    const float* fng   = (const float*)d_in[20];
    const float* fnb   = (const float*)d_in[21];
    const float* pq    = (const float*)d_in[22];
    const float* pWq   = (const float*)d_in[23];
    const float* pWk   = (const float*)d_in[24];
    const float* pWv   = (const float*)d_in[25];
    const float* pbq   = (const float*)d_in[26];
    const float* pbk   = (const float*)d_in[27];
    const float* pbv   = (const float*)d_in[28];
    const float* pWo   = (const float*)d_in[29];
    const float* pbo   = (const float*)d_in[30];
    const float* plg   = (const float*)d_in[31];
    const float* plb   = (const float*)d_in[32];
    const float* clg   = (const float*)d_in[33];
    const float* clb   = (const float*)d_in[34];
    const float* cW    = (const float*)d_in[35];
    const float* cb    = (const float*)d_in[36];
    float* out = (float*)d_out;

    // ---- workspace layout ----
    float* xb    = (float*)d_ws;             // 1,048,576 f
    float* cosb  = xb + 1048576;             // 65,536 f
    float* sinb  = cosb + 65536;             // 65,536 f
    float* opart = sinb + 65536;             // 2,097,152 f (8 MB)
    float* lsumw = opart + 2097152;          // 65,536 f
    float* pws   = lsumw + 65536;            // 8,704 f
    float* qsb   = pws + 8704;               // 256 f
    float* pbkv  = qsb + 256;                // 512 f
    bf16* ybf    = (bf16*)(pbkv + 512);      // 1,048,576 bf16
    bf16* qb     = ybf + 1048576;            // 1,048,576 bf16
    bf16* kb     = qb + 1048576;             // 1,048,576 bf16
    bf16* vb     = kb + 1048576;             // 1,048,576 bf16
    bf16* aob    = vb + 1048576;             // 1,048,576 bf16
    bf16* hb     = (bf16*)opart;             // FFN hidden aliases opart (8 MB)
    bf16* h8     = (bf16*)opart;             // tok hidden (pre-layers)
    bf16* pkv    = (bf16*)opart;             // pool K|V (4096x512) post-layers
    bf16* WTq    = aob + 1048576;            // 1,179,648 bf16
    bf16* WTo    = WTq + 1179648;            //   393,216 bf16
    bf16* WT1    = WTo + 393216;             // 1,572,864 bf16
    bf16* WT2    = WT1 + 1572864;            // 1,572,864 bf16
    bf16* WTpk   = WT2 + 1572864;            //    65,536 bf16 (contiguous with
    bf16* WTpv   = WTpk + 65536;             //    65,536 bf16  WTpv: 512x256)
    bf16* WTt2   = WTpv + 65536;             //    65,536 bf16

    // ---- weight convert/transpose (single launch) ----
    wt_all_kernel<<<4800, 256, 0, stream>>>(Wqkv, Wout, fW1, fW2, pWk, pWv, tokW2,
                                            WTq, WTo, WT1, WT2, WTpk, WTpv, WTt2);

    // ---- token embed ----
    tok_hid_kernel<<<NROWS / 4, 256, 0, stream>>>(feat, bid, emb, tokW1, tokb1,
                                                  h8, cosb, sinb);
    gemm64_kernel<3><<<dim3(64, 4), 256, 0, stream>>>(h8, WTt2, tokb2, xb, 256, 256);

    for (int i = 0; i < NLAYER; i++) {
        ln_bf16_kernel<<<NROWS / 4, 256, 0, stream>>>(
            xb, ln1g + i * DMODEL, ln1b + i * DMODEL, ybf);
        gemm_qkv_kernel<<<dim3(64, 12), 256, 0, stream>>>(
            ybf, WTq + (size_t)i * 196608, bqkv + i * 768, cosb, sinb, qb, kb, vb);
        attn_mfma_kernel<<<1024, 256, 0, stream>>>(qb, kb, vb, opart, lsumw);
        attn_merge_kernel<<<1024, 256, 0, stream>>>(opart, lsumw, aob);
        gemm64_kernel<1><<<dim3(64, 4), 256, 0, stream>>>(
            aob, WTo + (size_t)i * 65536, bout + i * DMODEL, xb, 256, 256);
        ln_bf16_kernel<<<NROWS / 4, 256, 0, stream>>>(
            xb, ln2g + i * DMODEL, ln2b + i * DMODEL, ybf);
        gemm64_kernel<2><<<dim3(64, 16), 256, 0, stream>>>(
            ybf, WT1 + (size_t)i * 262144, fb1 + i * DFF, hb, 256, 1024);
        gemm64_kernel<1><<<dim3(64, 4), 256, 0, stream>>>(
            hb, WT2 + (size_t)i * 262144, fb2 + i * DMODEL, xb, 1024, 256);
    }
    // final LN + pooling (K and V projections in ONE N=512 GEMM)
    ln_bf16_kernel<<<NROWS / 4, 256, 0, stream>>>(xb, fng, fnb, ybf);
    pool_qproj_kernel<<<1, 256, 0, stream>>>(pq, pWq, pbq, pbk, pbv, qsb, pbkv);
    gemm64_kernel<0><<<dim3(64, 8), 256, 0, stream>>>(ybf, WTpk, pbkv, pkv, 256, 512);
    pool_part_kernel<<<16 * NCHUNK, 256, 0, stream>>>(qsb, pkv, pws);
    pool_head_kernel<<<NBATCH, 256, 0, stream>>>(pws, pWo, pbo, plg, plb,
                                                 clg, clb, cW, cb, out);
}